// Round 12
// baseline (387.942 us; speedup 1.0000x reference)
//
#include <hip/hip_runtime.h>
#include <hip/hip_bf16.h>
#include <stdint.h>

#define RANK 32
#define SCALE (1.0f / 32.0f)

typedef __bf16 bf16x8 __attribute__((ext_vector_type(8)));
typedef float f32x4 __attribute__((ext_vector_type(4)));

// ---------------------------------------------------------------------------
// async global->LDS, 16B per lane
// ---------------------------------------------------------------------------
__device__ __forceinline__ void gload16(const void* g, void* l) {
  __builtin_amdgcn_global_load_lds(
      (const __attribute__((address_space(1))) unsigned int*)g,
      (__attribute__((address_space(3))) unsigned int*)l, 16, 0, 0);
}

__device__ __forceinline__ unsigned short f2bf(float f) {
  __hip_bfloat16 h = __float2bfloat16(f);
  return *reinterpret_cast<unsigned short*>(&h);
}

// ---------------------------------------------------------------------------
// Bt[o][r] = B[r][o]
// ---------------------------------------------------------------------------
__global__ __launch_bounds__(256) void transpose_B_k(const float* __restrict__ B,
                                                     float* __restrict__ Bt,
                                                     int Dout) {
  int idx = blockIdx.x * 256 + threadIdx.x;
  int r = idx / Dout;
  int o = idx - r * Dout;
  Bt[(long long)o * RANK + r] = B[idx];
}

// ---------------------------------------------------------------------------
// W' = W + SCALE * (A@B)^T, cast bf16, PRE-FRAGMENTED (R10 layout, 16x16):
//   Wbf[nb][kb][slot][e] ; nb=o>>4, kb=i>>5, slot=((i&31)>>3)*16+(o&15), e=i&7
// A wave's B-fragment (nb,kb) is a contiguous 1KB block, lane l reads 16B at
// +l*16 = exactly the mfma_16x16x32 B operand (l&15=col, l>>4=k-quarter).
// ---------------------------------------------------------------------------
__global__ __launch_bounds__(256) void merge_W_k(const float* __restrict__ W,
                                                 const float* __restrict__ A,
                                                 const float* __restrict__ Bt,
                                                 unsigned short* __restrict__ Wbf,
                                                 int Din, int Dout) {
  __shared__ float sB[16 * RANK];
  int nib = Din / 256;
  int ib = blockIdx.x % nib;
  int ob = blockIdx.x / nib;
  int i0 = ib * 256, o0 = ob * 16;
  int t = threadIdx.x;

  if (t < 128) {
    reinterpret_cast<float4*>(sB)[t] =
        reinterpret_cast<const float4*>(Bt + (long long)o0 * RANK)[t];
  }

  float a[RANK];
  const float4* Ap = reinterpret_cast<const float4*>(A + (long long)(i0 + t) * RANK);
#pragma unroll
  for (int c = 0; c < RANK / 4; ++c) {
    float4 v = Ap[c];
    a[c * 4 + 0] = v.x; a[c * 4 + 1] = v.y;
    a[c * 4 + 2] = v.z; a[c * 4 + 3] = v.w;
  }
  __syncthreads();

  int i = i0 + t;
  int KB = Din / 32;
  long long fragrow = (long long)(o0 >> 4) * KB + (i >> 5);  // nb*KB + kb
  int slot_base = ((i & 31) >> 3) * 16;                       // + o
  int e = i & 7;

  for (int o = 0; o < 16; ++o) {
    float d = 0.f;
#pragma unroll
    for (int j = 0; j < RANK; ++j) d += a[j] * sB[o * RANK + j];
    long long off = (long long)(o0 + o) * Din + i;
    float w = __builtin_nontemporal_load(&W[off]);
    Wbf[fragrow * 512 + (slot_base + o) * 8 + e] = f2bf(w + SCALE * d);
  }
}

// ---------------------------------------------------------------------------
// x fp32 -> bf16, 8 elems/thread (nt loads via native ext_vector)
// ---------------------------------------------------------------------------
__global__ __launch_bounds__(256) void cast_x_k(const float* __restrict__ in,
                                                unsigned short* __restrict__ out,
                                                long long n8) {
  long long i = (long long)blockIdx.x * 256 + threadIdx.x;
  if (i >= n8) return;
  const f32x4* in4 = reinterpret_cast<const f32x4*>(in) + i * 2;
  f32x4 v0 = __builtin_nontemporal_load(in4);
  f32x4 v1 = __builtin_nontemporal_load(in4 + 1);
  union { unsigned short u[8]; uint4 q; } p;
  p.u[0] = f2bf(v0.x); p.u[1] = f2bf(v0.y); p.u[2] = f2bf(v0.z); p.u[3] = f2bf(v0.w);
  p.u[4] = f2bf(v1.x); p.u[5] = f2bf(v1.y); p.u[6] = f2bf(v1.z); p.u[7] = f2bf(v1.w);
  reinterpret_cast<uint4*>(out)[i] = p.q;
}

// ---------------------------------------------------------------------------
// R12: 256x256 / BK=32 / 8 waves (2Mx4N) / ONE phase per K32-tile /
// 3-buffer LDS rotation (48KB) / stage-ahead-3 / B direct from global.
//
// Phase X: [GATE vmcnt(2)+barrier] [LOADB Bv(X+1)->other bank]
//          [stage Ra(X+3)->buf[X%3], 2 gloads] [8 ds_read aF(X+1)<-buf[(X+1)%3]]
//          [sched_barrier(0)] [setprio 32xMFMA tile X (aF/Bv current bank)]
//
// In-order vmcnt ledger (per-phase issue order: Bv first, Ra second):
//   At gate X outstanding (old->new): Ra(X+1)@X-2 drained earlier...
//   actually: {Bv(X)[4]@X-1 after Ra(X+2)? no: X-1 issued Bv(X) THEN Ra(X+2)}
//   => outstanding at gate X: [Ra(X+1) already drained by gate X-1? No:]
//   gate X-1 drained thru Bv(X-1), leaving {Ra(X+1)[2]@X-2, Bv(X)[4]@X-1,
//   Ra(X+2)[2]@X-1}. Gate X drains thru Bv(X) (also drains older Ra(X+1),
//   needed for THIS phase's reads) -> leaves Ra(X+2)[2] -> vmcnt(2).
// Slack: Bv 1 phase (~1300cy), Ra 2-3 phases. Tail: gates at X=126,127 are
// vmcnt(0) (nothing newer outstanding).
// LDS WAR: stage Ra(X+3)->buf[X%3]; last reads of buf[X%3] = aF(X) reads at
// phase X-1, lgkm-drained before MFMA(X-1), barrier-separated from stage.
// Reads of tile X+3 happen at phase X+2 whose gate drains Ra(X+3) (older
// than Bv(X+2)). Swizzle: chunk ^= (row^row>>2)&3 both sides (proven R7+).
// ---------------------------------------------------------------------------
__device__ __forceinline__ void stage1(const unsigned short* g, int K, int koff,
                                       int row0, unsigned short* ldsbase,
                                       int t, int wid) {
  int r = t >> 2;                               // 0..127 local row
  int cg = (t & 3) ^ ((r ^ (r >> 2)) & 3);      // inverse-swizzled 16B chunk
  gload16(g + (long long)(row0 + r) * K + koff + cg * 8,
          ldsbase + row0 * 32 + wid * 512);
}

__device__ __forceinline__ int swz_off32(int rowl, int k) {
  return rowl * 32 + ((((k) >> 3) ^ ((rowl ^ (rowl >> 2)) & 3)) << 3);
}

__global__ __launch_bounds__(512, 2) void gemm256_bias_k(
    const unsigned short* __restrict__ Xb,    // [M][K] bf16
    const unsigned short* __restrict__ Wbf,   // fragged [N/16][K/32][64][8]
    const float* __restrict__ bias,           // [N]
    float* __restrict__ Out,                  // [M][N] fp32
    int M, int N, int K) {
  __shared__ unsigned short As[3][256 * 32];  // 48 KiB, 3-buffer rotation

  int nbn = N / 256;
  int cpx = gridDim.x >> 3;
  int bid = blockIdx.x;
  int xcd = bid & 7, local = bid >> 3;
  int bm, bn;
  int mrows = cpx / nbn;
  if (mrows * nbn == cpx) {
    bn = local / mrows;
    bm = xcd * mrows + (local - bn * mrows);   // bm-fastest: B-panel L2-hot
  } else {
    int swz = xcd * cpx + local;
    bm = swz / nbn; bn = swz % nbn;
  }

  int t = threadIdx.x;
  int wid = t >> 6, lane = t & 63;
  int wr = wid >> 2, wc = wid & 3;             // 2x4 wave grid
  int lr = lane & 15, kq = (lane >> 4) * 8;
  int wr64 = wr * 64, wc32 = wc * 32;

  const unsigned short* ga = Xb + (long long)bm * 256 * K;
  const int KB = K / 32;                        // 128
  const unsigned short* gbf = Wbf + ((long long)(bn * 16 + wc * 2) * KB) * 512
                                  + lane * 8;

  f32x4 acc[8][4] = {};
  bf16x8 aF0[8], aF1[8], Bv0[4], Bv1[4];

#define LDA(BUF, ROWBASE) \
  (*(const bf16x8*)&As[BUF][swz_off32((ROWBASE) + lr, kq)])

#define GATE(NSTR) \
  asm volatile("s_waitcnt vmcnt(" NSTR ")" ::: "memory"); \
  __builtin_amdgcn_s_barrier();

#define READ_AF(AF, BUF) \
  AF[0] = LDA(BUF, wr64);            AF[1] = LDA(BUF, wr64 + 16); \
  AF[2] = LDA(BUF, wr64 + 32);       AF[3] = LDA(BUF, wr64 + 48); \
  AF[4] = LDA(BUF, 128 + wr64);      AF[5] = LDA(BUF, 128 + wr64 + 16); \
  AF[6] = LDA(BUF, 128 + wr64 + 32); AF[7] = LDA(BUF, 128 + wr64 + 48);

#define LOADB(BV, T) { \
  const unsigned short* fb = gbf + (long long)(T) * 512;               \
  BV[0] = *(const bf16x8*)(fb);                                        \
  BV[1] = *(const bf16x8*)(fb + (long long)KB * 512);                  \
  BV[2] = *(const bf16x8*)(fb + (long long)8 * KB * 512);              \
  BV[3] = *(const bf16x8*)(fb + (long long)9 * KB * 512); }

#define MFMA32(AF, BF)                                                       \
  __builtin_amdgcn_sched_barrier(0);                                         \
  __builtin_amdgcn_s_setprio(1);                                             \
  _Pragma("unroll")                                                          \
  for (int m = 0; m < 8; ++m)                                                \
    _Pragma("unroll")                                                        \
    for (int n = 0; n < 4; ++n)                                              \
      acc[m][n] = __builtin_amdgcn_mfma_f32_16x16x32_bf16(                   \
          AF[m], BF[n], acc[m][n], 0, 0, 0);                                 \
  __builtin_amdgcn_s_setprio(0);

  // PH(X): gate vmcnt(2); load Bv(X+1)->BVN; stage Ra(X+3)->buf SB (opt);
  // read aF(X+1)<-buf RB; MFMA tile X with AFU/BVU.
#define PH(AFU, AFN, BVU, BVN, RB, SB, XX, DOST)                             \
  GATE("2")                                                                  \
  LOADB(BVN, (XX) + 1)                                                       \
  if (DOST) {                                                                \
    stage1(ga, K, ((XX) + 3) * 32, 0,   &As[SB][0], t, wid);                 \
    stage1(ga, K, ((XX) + 3) * 32, 128, &As[SB][0], t, wid);                 \
  }                                                                          \
  READ_AF(AFN, RB)                                                           \
  MFMA32(AFU, BVU)

  // ---- prologue: Ra0->buf0, Ra1->buf1, Bv0, Ra2->buf2 (10 items);
  // vmcnt(8) drains Ra0; read aF(0).
  stage1(ga, K, 0,  0,   &As[0][0], t, wid);
  stage1(ga, K, 0,  128, &As[0][0], t, wid);
  stage1(ga, K, 32, 0,   &As[1][0], t, wid);
  stage1(ga, K, 32, 128, &As[1][0], t, wid);
  LOADB(Bv0, 0)
  stage1(ga, K, 64, 0,   &As[2][0], t, wid);
  stage1(ga, K, 64, 128, &As[2][0], t, wid);
  asm volatile("s_waitcnt vmcnt(8)" ::: "memory");
  __builtin_amdgcn_s_barrier();
  READ_AF(aF0, 0)

  // ---- main loop: X = 6k .. 6k+5, k=0..19 (X=0..119); buffer idx X%3,
  // bank parity X&1 — all static per slot.
  for (int k = 0; k < 20; ++k) {
    int X = 6 * k;
    PH(aF0, aF1, Bv0, Bv1, 1, 0, X + 0, 1)
    PH(aF1, aF0, Bv1, Bv0, 2, 1, X + 1, 1)
    PH(aF0, aF1, Bv0, Bv1, 0, 2, X + 2, 1)
    PH(aF1, aF0, Bv1, Bv0, 1, 0, X + 3, 1)
    PH(aF0, aF1, Bv0, Bv1, 2, 1, X + 4, 1)
    PH(aF1, aF0, Bv1, Bv0, 0, 2, X + 5, 1)
  }
  // ---- X=120..125 (stage allowed through X=124; X=125 stages nothing)
  PH(aF0, aF1, Bv0, Bv1, 1, 0, 120, 1)
  PH(aF1, aF0, Bv1, Bv0, 2, 1, 121, 1)
  PH(aF0, aF1, Bv0, Bv1, 0, 2, 122, 1)
  PH(aF1, aF0, Bv1, Bv0, 1, 0, 123, 1)
  PH(aF0, aF1, Bv0, Bv1, 2, 1, 124, 1)
  PH(aF1, aF0, Bv1, Bv0, 0, 2, 125, 0)
  // ---- X=126: drain everything older than (nothing newer than Bv126)
  GATE("0")
  LOADB(Bv1, 127)
  READ_AF(aF1, 1)          // tile 127 lives in buf 127%3 = 1
  MFMA32(aF0, Bv0)
  // ---- X=127: drain Bv127; regs only
  GATE("0")
  MFMA32(aF1, Bv1)

#undef LDA
#undef GATE
#undef READ_AF
#undef LOADB
#undef MFMA32
#undef PH

  // epilogue (nt stores), output map as R4/R6/R10:
  // rows: m<4 -> wr64 + m*16 ; m>=4 -> 128 + wr64 + (m-4)*16
  // cols: n<2 -> wc32 + n*16 ; n>=2 -> 128 + wc32 + (n-2)*16
  int rq = (lane >> 4) * 4;
#pragma unroll
  for (int n = 0; n < 4; ++n) {
    int gc = bn * 256 + (n >= 2 ? 128 : 0) + wc32 + (n & 1) * 16 + lr;
    float bv = bias[gc];
#pragma unroll
    for (int m = 0; m < 8; ++m) {
      long long gr = (long long)bm * 256 + (m >= 4 ? 128 : 0) + wr64 + (m & 3) * 16 + rq;
#pragma unroll
      for (int v = 0; v < 4; ++v)
        __builtin_nontemporal_store(acc[m][n][v] + bv, &Out[(gr + v) * N + gc]);
    }
  }
}

// ---------------------------------------------------------------------------
extern "C" void kernel_launch(void* const* d_in, const int* in_sizes, int n_in,
                              void* d_out, int out_size, void* d_ws, size_t ws_size,
                              hipStream_t stream) {
  const float* x    = (const float*)d_in[0];
  const float* W    = (const float*)d_in[1];
  const float* bias = (const float*)d_in[2];
  const float* A    = (const float*)d_in[3];
  const float* B    = (const float*)d_in[4];

  int Din  = in_sizes[3] / RANK;                 // 4096
  int Dout = in_sizes[4] / RANK;                 // 4096
  long long M = (long long)in_sizes[0] / Din;    // 8192

  size_t xb_bytes = (size_t)M * Din * 2;
  size_t wb_bytes = (size_t)Dout * Din * 2;
  size_t bt_bytes = (size_t)Dout * RANK * 4;
  if (ws_size < xb_bytes + wb_bytes + bt_bytes) return;

  char* ws = (char*)d_ws;
  unsigned short* Xb  = (unsigned short*)ws;
  unsigned short* Wbf = (unsigned short*)(ws + xb_bytes);
  float* Bt           = (float*)(ws + xb_bytes + wb_bytes);

  transpose_B_k<<<dim3((Dout * RANK) / 256), dim3(256), 0, stream>>>(B, Bt, Dout);
  merge_W_k<<<dim3((Dout / 16) * (Din / 256)), dim3(256), 0, stream>>>(W, A, Bt, Wbf, Din, Dout);
  long long n8 = M * Din / 8;
  cast_x_k<<<dim3((unsigned)(n8 / 256)), dim3(256), 0, stream>>>(x, Xb, n8);
  gemm256_bias_k<<<dim3((unsigned)((M / 256) * (Dout / 256))), dim3(512), 0, stream>>>(
      Xb, Wbf, bias, (float*)d_out, (int)M, Dout, Din);
}

// Round 14
// 376.899 us; speedup vs baseline: 1.0293x; 1.0293x over previous
//
#include <hip/hip_runtime.h>
#include <hip/hip_bf16.h>
#include <stdint.h>

#define RANK 32
#define SCALE (1.0f / 32.0f)

typedef __bf16 bf16x8 __attribute__((ext_vector_type(8)));
typedef float f32x4 __attribute__((ext_vector_type(4)));

// ---------------------------------------------------------------------------
// async global->LDS, 16B per lane
// ---------------------------------------------------------------------------
__device__ __forceinline__ void gload16(const void* g, void* l) {
  __builtin_amdgcn_global_load_lds(
      (const __attribute__((address_space(1))) unsigned int*)g,
      (__attribute__((address_space(3))) unsigned int*)l, 16, 0, 0);
}

__device__ __forceinline__ unsigned short f2bf(float f) {
  __hip_bfloat16 h = __float2bfloat16(f);
  return *reinterpret_cast<unsigned short*>(&h);
}

// ---------------------------------------------------------------------------
// Bt[o][r] = B[r][o]
// ---------------------------------------------------------------------------
__global__ __launch_bounds__(256) void transpose_B_k(const float* __restrict__ B,
                                                     float* __restrict__ Bt,
                                                     int Dout) {
  int idx = blockIdx.x * 256 + threadIdx.x;
  int r = idx / Dout;
  int o = idx - r * Dout;
  Bt[(long long)o * RANK + r] = B[idx];
}

// ---------------------------------------------------------------------------
// W' = W + SCALE * (A@B)^T, cast bf16, PRE-FRAGMENTED (R10 layout):
//   Wbf[nb][kb][slot][e] ; nb=o>>4, kb=i>>5, slot=((i&31)>>3)*16+(o&15), e=i&7
// ---------------------------------------------------------------------------
__global__ __launch_bounds__(256) void merge_W_k(const float* __restrict__ W,
                                                 const float* __restrict__ A,
                                                 const float* __restrict__ Bt,
                                                 unsigned short* __restrict__ Wbf,
                                                 int Din, int Dout) {
  __shared__ float sB[16 * RANK];
  int nib = Din / 256;
  int ib = blockIdx.x % nib;
  int ob = blockIdx.x / nib;
  int i0 = ib * 256, o0 = ob * 16;
  int t = threadIdx.x;

  if (t < 128) {
    reinterpret_cast<float4*>(sB)[t] =
        reinterpret_cast<const float4*>(Bt + (long long)o0 * RANK)[t];
  }

  float a[RANK];
  const float4* Ap = reinterpret_cast<const float4*>(A + (long long)(i0 + t) * RANK);
#pragma unroll
  for (int c = 0; c < RANK / 4; ++c) {
    float4 v = Ap[c];
    a[c * 4 + 0] = v.x; a[c * 4 + 1] = v.y;
    a[c * 4 + 2] = v.z; a[c * 4 + 3] = v.w;
  }
  __syncthreads();

  int i = i0 + t;
  int KB = Din / 32;
  long long fragrow = (long long)(o0 >> 4) * KB + (i >> 5);  // nb*KB + kb
  int slot_base = ((i & 31) >> 3) * 16;                       // + o
  int e = i & 7;

  for (int o = 0; o < 16; ++o) {
    float d = 0.f;
#pragma unroll
    for (int j = 0; j < RANK; ++j) d += a[j] * sB[o * RANK + j];
    long long off = (long long)(o0 + o) * Din + i;
    float w = __builtin_nontemporal_load(&W[off]);
    Wbf[fragrow * 512 + (slot_base + o) * 8 + e] = f2bf(w + SCALE * d);
  }
}

// ---------------------------------------------------------------------------
// x fp32 -> bf16, 8 elems/thread (nt loads via native ext_vector)
// ---------------------------------------------------------------------------
__global__ __launch_bounds__(256) void cast_x_k(const float* __restrict__ in,
                                                unsigned short* __restrict__ out,
                                                long long n8) {
  long long i = (long long)blockIdx.x * 256 + threadIdx.x;
  if (i >= n8) return;
  const f32x4* in4 = reinterpret_cast<const f32x4*>(in) + i * 2;
  f32x4 v0 = __builtin_nontemporal_load(in4);
  f32x4 v1 = __builtin_nontemporal_load(in4 + 1);
  union { unsigned short u[8]; uint4 q; } p;
  p.u[0] = f2bf(v0.x); p.u[1] = f2bf(v0.y); p.u[2] = f2bf(v0.z); p.u[3] = f2bf(v0.w);
  p.u[4] = f2bf(v1.x); p.u[5] = f2bf(v1.y); p.u[6] = f2bf(v1.z); p.u[7] = f2bf(v1.w);
  reinterpret_cast<uint4*>(out)[i] = p.q;
}

// ---------------------------------------------------------------------------
// R14 = R13 with the read-region/unit-region alignment bug fixed:
// wave wr now owns rows wr*32+{0..31} (lo, inside Ra1 rows 0..63) and
// 64+wr*32+{0..31} (hi, inside Ra2 rows 64..127) — every ds_read region is
// covered exactly by the unit its gate drains (R13 had wr=1's aL reading
// Ra2's region while Ra2(X+1) was still in flight -> stale LDS).
//
// 128x128 / BK=32 / 4 waves (2Mx2N) / A-only LDS 16KB dbuf / B direct from
// global (fragged Wbf) / R10's proven 2-phase ledger / 3 blocks per CU
// (m97/m114 mechanism: independent blocks cover each other's gate stalls).
//
// Units: Ra1(X)=rows0:64, Ra2(X)=rows64:128 (1 gload each); Bv(X)=4 loads.
// PH1(X): gate vmcnt(1) [drains Ra2(X)+Bv(X); leaves Ra1(X+1)];
//         stage Ra2(X+1)->As[(X+1)&1]; LOADB Bv(X+1); read aH(X); 8 MFMA lo
// PH2(X): gate vmcnt(5) [drains Ra1(X+1); leaves Ra2(X+1),Bv(X+1)];
//         stage Ra1(X+2)->As[X&1]; read aL(X+1); 8 MFMA hi
// Tail: 1 -> 5 -> 0.  Prologue: Ra1(0),Ra2(0),Bv(0),Ra1(1); vmcnt(1).
// Swizzle: chunk ^= (row ^ row>>2)&3 both sides (proven R7+).
// ---------------------------------------------------------------------------
__device__ __forceinline__ void stage1(const unsigned short* g, int K, int koff,
                                       int row0, unsigned short* ldsbase,
                                       int t, int wid) {
  int r = t >> 2;                               // 0..63 local row
  int cg = (t & 3) ^ ((r ^ (r >> 2)) & 3);      // inverse-swizzled 16B chunk
  gload16(g + (long long)(row0 + r) * K + koff + cg * 8,
          ldsbase + row0 * 32 + wid * 512);
}

__device__ __forceinline__ int swz_off32(int rowl, int k) {
  return rowl * 32 + ((((k) >> 3) ^ ((rowl ^ (rowl >> 2)) & 3)) << 3);
}

__global__ __launch_bounds__(256, 3) void gemm128_bias_k(
    const unsigned short* __restrict__ Xb,    // [M][K] bf16
    const unsigned short* __restrict__ Wbf,   // fragged [N/16][K/32][64][8]
    const float* __restrict__ bias,           // [N]
    float* __restrict__ Out,                  // [M][N] fp32
    int M, int N, int K) {
  __shared__ unsigned short As[2][128 * 32];  // 16 KiB

  int nbn = N / 128;                           // 32
  int cpx = gridDim.x >> 3;                    // 256
  int bid = blockIdx.x;
  int xcd = bid & 7, local = bid >> 3;
  int bm, bn;
  int mrows = cpx / nbn;                       // 8
  if (mrows * nbn == cpx) {
    bn = local / mrows;
    bm = xcd * mrows + (local - bn * mrows);   // bm-fastest: B-panel L2-hot
  } else {
    int swz = xcd * cpx + local;
    bm = swz / nbn; bn = swz % nbn;
  }

  int t = threadIdx.x;
  int wid = t >> 6, lane = t & 63;
  int wr = wid >> 1, wc = wid & 1;             // 2x2 wave grid
  int lr = lane & 15, kq = (lane >> 4) * 8;
  int wr32 = wr * 32;

  const unsigned short* ga = Xb + (long long)bm * 128 * K;
  const int KB = K / 32;                        // 128
  // B frag rows nb0 = bn*8 + wc*4, frags +0..3 (cols wc*64 + n*16)
  const unsigned short* gbf = Wbf + ((long long)(bn * 8 + wc * 4) * KB) * 512
                                  + lane * 8;

  f32x4 acc[4][4] = {};
  bf16x8 aL0[2], aL1[2], aH0[2], aH1[2], Bv0[4], Bv1[4];

#define LDA(BUF, ROWBASE) \
  (*(const bf16x8*)&As[BUF][swz_off32((ROWBASE) + lr, kq)])

#define GATE(NSTR) \
  asm volatile("s_waitcnt vmcnt(" NSTR ")" ::: "memory"); \
  __builtin_amdgcn_s_barrier();

  // aH rows 64 + wr32 + {0,16}  (inside Ra2 unit: rows 64..127)
#define READ_AH(AH, BUF) \
  AH[0] = LDA(BUF, 64 + wr32); AH[1] = LDA(BUF, 64 + wr32 + 16);

  // aL rows wr32 + {0,16}       (inside Ra1 unit: rows 0..63)
#define READ_AL(AL, BUF) \
  AL[0] = LDA(BUF, wr32);      AL[1] = LDA(BUF, wr32 + 16);

#define LOADB(BV, T) { \
  const unsigned short* fb = gbf + (long long)(T) * 512;               \
  BV[0] = *(const bf16x8*)(fb);                                        \
  BV[1] = *(const bf16x8*)(fb + (long long)KB * 512);                  \
  BV[2] = *(const bf16x8*)(fb + (long long)2 * KB * 512);              \
  BV[3] = *(const bf16x8*)(fb + (long long)3 * KB * 512); }

#define MFMA8(AF, BF, MO)                                                    \
  __builtin_amdgcn_sched_barrier(0);                                         \
  __builtin_amdgcn_s_setprio(1);                                             \
  _Pragma("unroll")                                                          \
  for (int m = 0; m < 2; ++m)                                                \
    _Pragma("unroll")                                                        \
    for (int n = 0; n < 4; ++n)                                              \
      acc[(MO) + m][n] = __builtin_amdgcn_mfma_f32_16x16x32_bf16(            \
          AF[m], BF[n], acc[(MO) + m][n], 0, 0, 0);                          \
  __builtin_amdgcn_s_setprio(0);

  // ---- prologue: Ra1(0), Ra2(0), Bv(0), Ra1(1); vmcnt(1) leaves Ra1(1)
  stage1(ga, K, 0, 0,   &As[0][0], t, wid);    // Ra1(0)
  stage1(ga, K, 0, 64,  &As[0][0], t, wid);    // Ra2(0)
  LOADB(Bv0, 0)                                 // Bv(0) [4]
  stage1(ga, K, 32, 0,  &As[1][0], t, wid);    // Ra1(1)
  asm volatile("s_waitcnt vmcnt(1)" ::: "memory");
  __builtin_amdgcn_s_barrier();
  READ_AL(aL0, 0)

  // ---- steady loop: j covers X=2j (As[0]) and X=2j+1 (As[1]); j=0..62
  for (int j = 0; j < 63; ++j) {
    int ko = j * 64;  // 2j*32
    // PH1(X=2j): stage Ra2(X+1); load Bv(X+1); read aH(X); MFMA lo
    GATE("1")
    stage1(ga, K, ko + 32, 64, &As[1][0], t, wid);
    LOADB(Bv1, 2 * j + 1)
    READ_AH(aH0, 0)
    MFMA8(aL0, Bv0, 0)
    // PH2(X=2j): stage Ra1(X+2); read aL(X+1); MFMA hi
    GATE("5")
    stage1(ga, K, ko + 64, 0, &As[0][0], t, wid);
    READ_AL(aL1, 1)
    MFMA8(aH0, Bv0, 2)
    // PH1(X=2j+1): stage Ra2(X+2); load Bv(X+2); read aH(X+1); MFMA lo
    GATE("1")
    stage1(ga, K, ko + 64, 64, &As[0][0], t, wid);
    LOADB(Bv0, 2 * j + 2)
    READ_AH(aH1, 1)
    MFMA8(aL1, Bv1, 0)
    // PH2(X=2j+1): stage Ra1(X+3); read aL(X+2); MFMA hi
    GATE("5")
    stage1(ga, K, ko + 96, 0, &As[1][0], t, wid);
    READ_AL(aL0, 0)
    MFMA8(aH1, Bv1, 2)
  }

  // ---- peeled tail: X=126 (As[0]), X=127 (As[1])
  GATE("1")
  stage1(ga, K, 127 * 32, 64, &As[1][0], t, wid);    // Ra2(127)
  LOADB(Bv1, 127)
  READ_AH(aH0, 0)
  MFMA8(aL0, Bv0, 0)
  GATE("5")
  READ_AL(aL1, 1)
  MFMA8(aH0, Bv0, 2)
  GATE("0")
  READ_AH(aH1, 1)
  MFMA8(aL1, Bv1, 0)
  MFMA8(aH1, Bv1, 2)

#undef LDA
#undef GATE
#undef READ_AH
#undef READ_AL
#undef LOADB
#undef MFMA8

  // epilogue (nt stores): rows bm*128 + (m>=2?64:0) + wr32 + (m&1)*16 + rq;
  // cols bn*128 + wc*64 + n*16 + lr
  int rq = (lane >> 4) * 4;
#pragma unroll
  for (int n = 0; n < 4; ++n) {
    int gc = bn * 128 + wc * 64 + n * 16 + lr;
    float bv = bias[gc];
#pragma unroll
    for (int m = 0; m < 4; ++m) {
      long long gr = (long long)bm * 128 + (m >= 2 ? 64 : 0) + wr32 + (m & 1) * 16 + rq;
#pragma unroll
      for (int v = 0; v < 4; ++v)
        __builtin_nontemporal_store(acc[m][n][v] + bv, &Out[(gr + v) * N + gc]);
    }
  }
}

// ---------------------------------------------------------------------------
extern "C" void kernel_launch(void* const* d_in, const int* in_sizes, int n_in,
                              void* d_out, int out_size, void* d_ws, size_t ws_size,
                              hipStream_t stream) {
  const float* x    = (const float*)d_in[0];
  const float* W    = (const float*)d_in[1];
  const float* bias = (const float*)d_in[2];
  const float* A    = (const float*)d_in[3];
  const float* B    = (const float*)d_in[4];

  int Din  = in_sizes[3] / RANK;                 // 4096
  int Dout = in_sizes[4] / RANK;                 // 4096
  long long M = (long long)in_sizes[0] / Din;    // 8192

  size_t xb_bytes = (size_t)M * Din * 2;
  size_t wb_bytes = (size_t)Dout * Din * 2;
  size_t bt_bytes = (size_t)Dout * RANK * 4;
  if (ws_size < xb_bytes + wb_bytes + bt_bytes) return;

  char* ws = (char*)d_ws;
  unsigned short* Xb  = (unsigned short*)ws;
  unsigned short* Wbf = (unsigned short*)(ws + xb_bytes);
  float* Bt           = (float*)(ws + xb_bytes + wb_bytes);

  transpose_B_k<<<dim3((Dout * RANK) / 256), dim3(256), 0, stream>>>(B, Bt, Dout);
  merge_W_k<<<dim3((Dout / 16) * (Din / 256)), dim3(256), 0, stream>>>(W, A, Bt, Wbf, Din, Dout);
  long long n8 = M * Din / 8;
  cast_x_k<<<dim3((unsigned)(n8 / 256)), dim3(256), 0, stream>>>(x, Xb, n8);
  gemm128_bias_k<<<dim3((unsigned)((M / 128) * (Dout / 128))), dim3(256), 0, stream>>>(
      Xb, Wbf, bias, (float*)d_out, (int)M, Dout, Din);
}